// Round 2
// baseline (1255.706 us; speedup 1.0000x reference)
//
#include <hip/hip_runtime.h>

// GCN encoder: 3x GCNConv (+self-loops, sym deg^-1/2 norm) + ELU + mean-pool.
// N=50000, E=800000, IN=128, HID=64, ZDIM=64, G=64. All f32.

#define IN_DIM 128
#define HID 64
#define ZDIM 64
#define N_GRAPHS 64

__device__ __forceinline__ float elu1(float x) {
    return x > 0.f ? x : expm1f(x);
}

__global__ void k_deg_init(float* __restrict__ deg, int n) {
    int i = blockIdx.x * blockDim.x + threadIdx.x;
    if (i < n) deg[i] = 1.0f;  // self-loop
}

__global__ void k_deg_count(const int* __restrict__ dst, float* __restrict__ deg, int E) {
    int e = blockIdx.x * blockDim.x + threadIdx.x;
    if (e < E) atomicAdd(&deg[dst[e]], 1.0f);
}

__global__ void k_dinv(float* __restrict__ deg, int n) {
    int i = blockIdx.x * blockDim.x + threadIdx.x;
    if (i < n) deg[i] = 1.0f / sqrtf(deg[i]);
}

__global__ void k_zero(float* __restrict__ p, int n) {
    int i = blockIdx.x * blockDim.x + threadIdx.x;
    if (i < n) p[i] = 0.0f;
}

// t[n,64] = x[n,128] @ W[128,64]; one wave per node, lane = out dim.
__global__ __launch_bounds__(256) void k_mm1(const float* __restrict__ x,
                                             const float* __restrict__ W,
                                             float* __restrict__ t, int n) {
    __shared__ float Wl[IN_DIM * HID];
    for (int i = threadIdx.x; i < IN_DIM * HID; i += 256) Wl[i] = W[i];
    __syncthreads();
    int lane = threadIdx.x & 63;
    int node = blockIdx.x * 4 + (threadIdx.x >> 6);
    if (node >= n) return;
    const float4* x4 = (const float4*)(x + (size_t)node * IN_DIM);
    float acc = 0.f;
#pragma unroll
    for (int k4 = 0; k4 < IN_DIM / 4; ++k4) {
        float4 xv = x4[k4];
        acc = fmaf(xv.x, Wl[(4 * k4 + 0) * HID + lane], acc);
        acc = fmaf(xv.y, Wl[(4 * k4 + 1) * HID + lane], acc);
        acc = fmaf(xv.z, Wl[(4 * k4 + 2) * HID + lane], acc);
        acc = fmaf(xv.w, Wl[(4 * k4 + 3) * HID + lane], acc);
    }
    t[(size_t)node * HID + lane] = acc;
}

// t2[n,64] = h @ Wmu, t3[n,64] = h @ Wsig (h[n,64]); fused, weights in LDS.
__global__ __launch_bounds__(256) void k_mm23(const float* __restrict__ h,
                                              const float* __restrict__ Wmu,
                                              const float* __restrict__ Wsig,
                                              float* __restrict__ t2,
                                              float* __restrict__ t3, int n) {
    __shared__ float Wl[2 * HID * ZDIM];
    for (int i = threadIdx.x; i < HID * ZDIM; i += 256) {
        Wl[i] = Wmu[i];
        Wl[HID * ZDIM + i] = Wsig[i];
    }
    __syncthreads();
    int lane = threadIdx.x & 63;
    int node = blockIdx.x * 4 + (threadIdx.x >> 6);
    if (node >= n) return;
    const float4* h4 = (const float4*)(h + (size_t)node * HID);
    float am = 0.f, as = 0.f;
#pragma unroll
    for (int k4 = 0; k4 < HID / 4; ++k4) {
        float4 hv = h4[k4];
        am = fmaf(hv.x, Wl[(4 * k4 + 0) * ZDIM + lane], am);
        am = fmaf(hv.y, Wl[(4 * k4 + 1) * ZDIM + lane], am);
        am = fmaf(hv.z, Wl[(4 * k4 + 2) * ZDIM + lane], am);
        am = fmaf(hv.w, Wl[(4 * k4 + 3) * ZDIM + lane], am);
        as = fmaf(hv.x, Wl[HID * ZDIM + (4 * k4 + 0) * ZDIM + lane], as);
        as = fmaf(hv.y, Wl[HID * ZDIM + (4 * k4 + 1) * ZDIM + lane], as);
        as = fmaf(hv.z, Wl[HID * ZDIM + (4 * k4 + 2) * ZDIM + lane], as);
        as = fmaf(hv.w, Wl[HID * ZDIM + (4 * k4 + 3) * ZDIM + lane], as);
    }
    t2[(size_t)node * ZDIM + lane] = am;
    t3[(size_t)node * ZDIM + lane] = as;
}

// out[i][j] = t[i][j] * dinv[i]^2  (self-loop message, initializes out)
__global__ void k_self_init(const float* __restrict__ t, const float* __restrict__ dinv,
                            float* __restrict__ out, int total) {
    int i = blockIdx.x * blockDim.x + threadIdx.x;
    if (i >= total) return;
    float di = dinv[i >> 6];
    out[i] = t[i] * di * di;
}

// out[dst] += t[src] * dinv[src]*dinv[dst]; one wave per edge, lane = dim.
__global__ __launch_bounds__(256) void k_agg_edges(const int* __restrict__ src,
                                                   const int* __restrict__ dst,
                                                   const float* __restrict__ dinv,
                                                   const float* __restrict__ t,
                                                   float* __restrict__ out, int E) {
    int e = blockIdx.x * 4 + (threadIdx.x >> 6);
    if (e >= E) return;
    int lane = threadIdx.x & 63;
    int s = src[e], d = dst[e];
    float norm = dinv[s] * dinv[d];
    float v = t[(size_t)s * 64 + lane] * norm;
    atomicAdd(&out[(size_t)d * 64 + lane], v);
}

__global__ void k_bias_elu(float* __restrict__ io, const float* __restrict__ b, int total) {
    int i = blockIdx.x * blockDim.x + threadIdx.x;
    if (i < total) io[i] = elu1(io[i] + b[i & 63]);
}

// per-node: v = elu(t + b); sum[batch[node]] += v; optional count.
__global__ __launch_bounds__(256) void k_pool(const float* __restrict__ t,
                                              const float* __restrict__ b,
                                              const int* __restrict__ batch,
                                              float* __restrict__ sum,
                                              float* __restrict__ cnt,
                                              int n, int do_count) {
    int node = blockIdx.x * 4 + (threadIdx.x >> 6);
    if (node >= n) return;
    int lane = threadIdx.x & 63;
    int g = batch[node];
    float v = elu1(t[(size_t)node * 64 + lane] + b[lane]);
    atomicAdd(&sum[g * 64 + lane], v);
    if (do_count && lane == 0) atomicAdd(&cnt[g], 1.0f);
}

__global__ void k_finalize(const float* __restrict__ smu, const float* __restrict__ ssig,
                           const float* __restrict__ cnt, float* __restrict__ out) {
    int i = blockIdx.x * blockDim.x + threadIdx.x;
    if (i >= N_GRAPHS * ZDIM) return;
    float c = fmaxf(cnt[i >> 6], 1.0f);
    out[i] = smu[i] / c;
    out[N_GRAPHS * ZDIM + i] = ssig[i] / c;
}

extern "C" void kernel_launch(void* const* d_in, const int* in_sizes, int n_in,
                              void* d_out, int out_size, void* d_ws, size_t ws_size,
                              hipStream_t stream) {
    const float* x    = (const float*)d_in[0];
    const int*   ei   = (const int*)d_in[1];
    const int*   batch= (const int*)d_in[2];
    // d_in[3] = num_graphs (scalar, known 64)
    const float* W1   = (const float*)d_in[4];
    const float* b1   = (const float*)d_in[5];
    const float* Wmu  = (const float*)d_in[6];
    const float* bmu  = (const float*)d_in[7];
    const float* Wsig = (const float*)d_in[8];
    const float* bsig = (const float*)d_in[9];
    float* out = (float*)d_out;

    const int n = in_sizes[0] / IN_DIM;   // 50000
    const int E = in_sizes[1] / 2;        // 800000
    const int* src = ei;
    const int* dst = ei + E;

    float* ws = (float*)d_ws;
    size_t off = 0;
    float* dinv = ws + off; off += 50048;          // deg -> dinv in place
    float* cnt  = ws + off; off += 64;
    float* smu  = ws + off; off += 4096;
    float* ssig = ws + off; off += 4096;
    off = (off + 15) & ~(size_t)15;
    const size_t BIG = (size_t)n * 64;
    float* A = ws + off; off += BIG;  // t1, later out_mu
    float* B = ws + off; off += BIG;  // out1/h, later out_sig
    float* C = ws + off; off += BIG;  // t2
    float* D = ws + off; off += BIG;  // t3

    const int total = n * 64;
    const int gN   = (n + 255) / 256;
    const int gE   = (E + 255) / 256;
    const int gT   = (total + 255) / 256;
    const int gNW  = (n + 3) / 4;     // one wave per node
    const int gEW  = (E + 3) / 4;     // one wave per edge

    // degree / normalization
    k_deg_init<<<gN, 256, 0, stream>>>(dinv, n);
    k_deg_count<<<gE, 256, 0, stream>>>(dst, dinv, E);
    k_dinv<<<gN, 256, 0, stream>>>(dinv, n);
    // zero pool accumulators (cnt+smu+ssig are contiguous: 64+4096+4096)
    k_zero<<<(8256 + 255) / 256, 256, 0, stream>>>(cnt, 8256);

    // layer 1: h = elu(agg(x@W1) + b1)
    k_mm1<<<gNW, 256, 0, stream>>>(x, W1, A, n);
    k_self_init<<<gT, 256, 0, stream>>>(A, dinv, B, total);
    k_agg_edges<<<gEW, 256, 0, stream>>>(src, dst, dinv, A, B, E);
    k_bias_elu<<<gT, 256, 0, stream>>>(B, b1, total);

    // layer 2/3 linear: t2 = h@Wmu, t3 = h@Wsig
    k_mm23<<<gNW, 256, 0, stream>>>(B, Wmu, Wsig, C, D, n);

    // aggregation mu -> A, sig -> B (t1 and h are dead now)
    k_self_init<<<gT, 256, 0, stream>>>(C, dinv, A, total);
    k_agg_edges<<<gEW, 256, 0, stream>>>(src, dst, dinv, C, A, E);
    k_self_init<<<gT, 256, 0, stream>>>(D, dinv, B, total);
    k_agg_edges<<<gEW, 256, 0, stream>>>(src, dst, dinv, D, B, E);

    // bias + elu + mean-pool sums
    k_pool<<<gNW, 256, 0, stream>>>(A, bmu, batch, smu, cnt, n, 1);
    k_pool<<<gNW, 256, 0, stream>>>(B, bsig, batch, ssig, cnt, n, 0);

    k_finalize<<<(N_GRAPHS * ZDIM + 255) / 256, 256, 0, stream>>>(smu, ssig, cnt, out);
}

// Round 3
// 986.862 us; speedup vs baseline: 1.2724x; 1.2724x over previous
//
#include <hip/hip_runtime.h>

// GCN encoder: 3x GCNConv (+self-loops, sym deg^-1/2 norm) + ELU + mean-pool.
// N=50000, E=800000, IN=128, HID=64, ZDIM=64, G=64. All f32.
// R2: batch is sorted -> per-graph block reduction (no pool atomics);
//     self-loop init fused into matmuls; bias+ELU fused into mm23 load.

#define IN_DIM 128
#define HID 64
#define ZDIM 64
#define N_GRAPHS 64

__device__ __forceinline__ float elu1(float x) {
    return x > 0.f ? x : expm1f(x);
}

__global__ void k_deg_init(float* __restrict__ deg, int n) {
    int i = blockIdx.x * blockDim.x + threadIdx.x;
    if (i < n) deg[i] = 1.0f;  // self-loop
}

__global__ void k_deg_count(const int* __restrict__ dst, float* __restrict__ deg, int E) {
    int e = blockIdx.x * blockDim.x + threadIdx.x;
    if (e < E) atomicAdd(&deg[dst[e]], 1.0f);
}

__global__ void k_dinv(float* __restrict__ deg, int n) {
    int i = blockIdx.x * blockDim.x + threadIdx.x;
    if (i < n) deg[i] = 1.0f / sqrtf(deg[i]);
}

// starts[g] = lower_bound(batch, g) for g in [0, 64]; batch is sorted.
__global__ void k_starts(const int* __restrict__ batch, int* __restrict__ starts, int n) {
    int g = threadIdx.x;
    if (g > N_GRAPHS) return;
    int lo = 0, hi = n;
    while (lo < hi) {
        int mid = (lo + hi) >> 1;
        if (batch[mid] < g) lo = mid + 1; else hi = mid;
    }
    starts[g] = lo;
}

// t[n,64] = x[n,128] @ W[128,64]; one wave per node, lane = out dim.
// Also writes the self-loop-initialized aggregation buffer o = t * dinv^2.
__global__ __launch_bounds__(256) void k_mm1(const float* __restrict__ x,
                                             const float* __restrict__ W,
                                             const float* __restrict__ dinv,
                                             float* __restrict__ t,
                                             float* __restrict__ o, int n) {
    __shared__ float Wl[IN_DIM * HID];
    for (int i = threadIdx.x; i < IN_DIM * HID; i += 256) Wl[i] = W[i];
    __syncthreads();
    int lane = threadIdx.x & 63;
    int node = blockIdx.x * 4 + (threadIdx.x >> 6);
    if (node >= n) return;
    const float4* x4 = (const float4*)(x + (size_t)node * IN_DIM);
    float acc = 0.f;
#pragma unroll
    for (int k4 = 0; k4 < IN_DIM / 4; ++k4) {
        float4 xv = x4[k4];
        acc = fmaf(xv.x, Wl[(4 * k4 + 0) * HID + lane], acc);
        acc = fmaf(xv.y, Wl[(4 * k4 + 1) * HID + lane], acc);
        acc = fmaf(xv.z, Wl[(4 * k4 + 2) * HID + lane], acc);
        acc = fmaf(xv.w, Wl[(4 * k4 + 3) * HID + lane], acc);
    }
    float di = dinv[node];
    t[(size_t)node * HID + lane] = acc;
    o[(size_t)node * HID + lane] = acc * di * di;
}

// h = elu(hraw + b1); t2 = h@Wmu -> C, t3 = h@Wsig -> D;
// omu = t2*di^2 -> A, osig = t3*di^2 -> B.
// NOTE: hraw and osig may alias (buffer B): each wave reads its entire row
// before writing it, and no other thread touches that row -> no __restrict__
// on those two.
__global__ __launch_bounds__(256) void k_mm23(const float* hraw,
                                              const float* __restrict__ b1,
                                              const float* __restrict__ Wmu,
                                              const float* __restrict__ Wsig,
                                              const float* __restrict__ dinv,
                                              float* __restrict__ t2,
                                              float* __restrict__ t3,
                                              float* __restrict__ omu,
                                              float* osig, int n) {
    __shared__ float Wl[2 * HID * ZDIM];
    __shared__ float bl[HID];
    for (int i = threadIdx.x; i < HID * ZDIM; i += 256) {
        Wl[i] = Wmu[i];
        Wl[HID * ZDIM + i] = Wsig[i];
    }
    if (threadIdx.x < HID) bl[threadIdx.x] = b1[threadIdx.x];
    __syncthreads();
    int lane = threadIdx.x & 63;
    int node = blockIdx.x * 4 + (threadIdx.x >> 6);
    if (node >= n) return;
    const float4* h4 = (const float4*)(hraw + (size_t)node * HID);
    float am = 0.f, as = 0.f;
#pragma unroll
    for (int k4 = 0; k4 < HID / 4; ++k4) {
        float4 hv = h4[k4];
        float h0 = elu1(hv.x + bl[4 * k4 + 0]);
        float h1 = elu1(hv.y + bl[4 * k4 + 1]);
        float h2 = elu1(hv.z + bl[4 * k4 + 2]);
        float h3 = elu1(hv.w + bl[4 * k4 + 3]);
        am = fmaf(h0, Wl[(4 * k4 + 0) * ZDIM + lane], am);
        am = fmaf(h1, Wl[(4 * k4 + 1) * ZDIM + lane], am);
        am = fmaf(h2, Wl[(4 * k4 + 2) * ZDIM + lane], am);
        am = fmaf(h3, Wl[(4 * k4 + 3) * ZDIM + lane], am);
        as = fmaf(h0, Wl[HID * ZDIM + (4 * k4 + 0) * ZDIM + lane], as);
        as = fmaf(h1, Wl[HID * ZDIM + (4 * k4 + 1) * ZDIM + lane], as);
        as = fmaf(h2, Wl[HID * ZDIM + (4 * k4 + 2) * ZDIM + lane], as);
        as = fmaf(h3, Wl[HID * ZDIM + (4 * k4 + 3) * ZDIM + lane], as);
    }
    float di = dinv[node];
    float d2 = di * di;
    t2[(size_t)node * ZDIM + lane] = am;
    t3[(size_t)node * ZDIM + lane] = as;
    omu[(size_t)node * ZDIM + lane] = am * d2;
    osig[(size_t)node * ZDIM + lane] = as * d2;
}

// out[dst] += t[src] * dinv[src]*dinv[dst]; one wave per edge, lane = dim.
__global__ __launch_bounds__(256) void k_agg_edges(const int* __restrict__ src,
                                                   const int* __restrict__ dst,
                                                   const float* __restrict__ dinv,
                                                   const float* __restrict__ t,
                                                   float* __restrict__ out, int E) {
    int e = blockIdx.x * 4 + (threadIdx.x >> 6);
    if (e >= E) return;
    int lane = threadIdx.x & 63;
    int s = src[e], d = dst[e];
    float norm = dinv[s] * dinv[d];
    float v = t[(size_t)s * 64 + lane] * norm;
    atomicAdd(&out[(size_t)d * 64 + lane], v);
}

// One block per graph: out[g][lane] = mean over nodes of elu(t + b).
// batch sorted -> contiguous node range [starts[g], starts[g+1]).
__global__ __launch_bounds__(512) void k_pool_graph(const float* __restrict__ t,
                                                    const float* __restrict__ b,
                                                    const int* __restrict__ starts,
                                                    float* __restrict__ out) {
    int g = blockIdx.x;
    int s = starts[g], e = starts[g + 1];
    int lane = threadIdx.x & 63;
    int w = threadIdx.x >> 6;  // 0..7
    float bias = b[lane];
    float acc = 0.f;
    for (int node = s + w; node < e; node += 8)
        acc += elu1(t[(size_t)node * 64 + lane] + bias);
    __shared__ float red[8][64];
    red[w][lane] = acc;
    __syncthreads();
    if (w == 0) {
        float sum = 0.f;
#pragma unroll
        for (int i = 0; i < 8; ++i) sum += red[i][lane];
        float c = fmaxf((float)(e - s), 1.0f);
        out[g * 64 + lane] = sum / c;
    }
}

extern "C" void kernel_launch(void* const* d_in, const int* in_sizes, int n_in,
                              void* d_out, int out_size, void* d_ws, size_t ws_size,
                              hipStream_t stream) {
    const float* x    = (const float*)d_in[0];
    const int*   ei   = (const int*)d_in[1];
    const int*   batch= (const int*)d_in[2];
    // d_in[3] = num_graphs (scalar, known 64)
    const float* W1   = (const float*)d_in[4];
    const float* b1   = (const float*)d_in[5];
    const float* Wmu  = (const float*)d_in[6];
    const float* bmu  = (const float*)d_in[7];
    const float* Wsig = (const float*)d_in[8];
    const float* bsig = (const float*)d_in[9];
    float* out = (float*)d_out;

    const int n = in_sizes[0] / IN_DIM;   // 50000
    const int E = in_sizes[1] / 2;        // 800000
    const int* src = ei;
    const int* dst = ei + E;

    float* ws = (float*)d_ws;
    size_t off = 0;
    float* dinv   = ws + off; off += 50048;   // deg -> dinv in place
    int*   starts = (int*)(ws + off); off += 80;  // 65 ints
    off = (off + 15) & ~(size_t)15;
    const size_t BIG = (size_t)n * 64;
    float* A = ws + off; off += BIG;  // t1, later out_mu
    float* B = ws + off; off += BIG;  // agg1 raw -> (elu in mm23), later out_sig
    float* C = ws + off; off += BIG;  // t2
    float* D = ws + off; off += BIG;  // t3

    const int gN   = (n + 255) / 256;
    const int gE   = (E + 255) / 256;
    const int gNW  = (n + 3) / 4;     // one wave per node
    const int gEW  = (E + 3) / 4;     // one wave per edge

    // degree / normalization / graph ranges
    k_deg_init<<<gN, 256, 0, stream>>>(dinv, n);
    k_deg_count<<<gE, 256, 0, stream>>>(dst, dinv, E);
    k_dinv<<<gN, 256, 0, stream>>>(dinv, n);
    k_starts<<<1, 128, 0, stream>>>(batch, starts, n);

    // layer 1: A = x@W1, B = A*di^2 (self-loop init); then edge scatter
    k_mm1<<<gNW, 256, 0, stream>>>(x, W1, dinv, A, B, n);
    k_agg_edges<<<gEW, 256, 0, stream>>>(src, dst, dinv, A, B, E);

    // layers 2/3 linear (h = elu(B + b1) on the fly): C=t2, D=t3; A/B -> self-init
    k_mm23<<<gNW, 256, 0, stream>>>(B, b1, Wmu, Wsig, dinv, C, D, A, B, n);

    // aggregation mu -> A, sig -> B
    k_agg_edges<<<gEW, 256, 0, stream>>>(src, dst, dinv, C, A, E);
    k_agg_edges<<<gEW, 256, 0, stream>>>(src, dst, dinv, D, B, E);

    // bias + elu + mean-pool straight to d_out (no atomics)
    k_pool_graph<<<N_GRAPHS, 512, 0, stream>>>(A, bmu, starts, out);
    k_pool_graph<<<N_GRAPHS, 512, 0, stream>>>(B, bsig, starts, out + N_GRAPHS * ZDIM);
}